// Round 7
// baseline (162.445 us; speedup 1.0000x reference)
//
#include <hip/hip_runtime.h>
#include <hip/hip_bf16.h>

constexpr int CN   = 32;
constexpr int CIN  = 64;
constexpr int CH   = 128;
constexpr int CW   = 128;
constexpr int COUT = 128;
constexpr int OHh  = 126;
constexpr int OWw  = 126;
constexpr int KTOT = 576;

typedef __attribute__((ext_vector_type(8))) short bf16x8;
typedef __attribute__((ext_vector_type(4))) float f32x4;

__device__ __forceinline__ unsigned short f2bf(float f) {
  union { float f; unsigned u; } v; v.f = f;
  unsigned u = v.u;
  u += 0x7FFFu + ((u >> 16) & 1u);   // RNE
  return (unsigned short)(u >> 16);
}

__device__ __forceinline__ unsigned packbf2(float a, float b) {
  union { __hip_bfloat162 h; unsigned u; } v;
  v.h = __float22bfloat162_rn(make_float2(a, b));   // v_cvt_pk_bf16_f32
  return v.u;
}

// ---- prep: W -> wt3, A-fragment-ordered: [p:18][wc:2][mi:4][lane:64][j:8] -----------
// p = G*3+kw, G = kh*2+half; co = wc*64+mi*16+(lane&15); ci = half*32+(lane>>4)*8+j.
__global__ void prep_wt3_kernel(const float* __restrict__ w,
                                unsigned short* __restrict__ wt3) {
  int e = blockIdx.x * 256 + threadIdx.x;
  if (e >= COUT * KTOT) return;
  int j = e & 7, lane = (e >> 3) & 63, mi = (e >> 9) & 3, wc = (e >> 11) & 1;
  int p = e >> 12;                 // 0..17
  int G = p / 3, kw = p - G * 3;
  int kh = G >> 1, half = G & 1;
  int co = wc * 64 + mi * 16 + (lane & 15);
  int ci = half * 32 + (lane >> 4) * 8 + j;
  wt3[e] = f2bf(w[co * 576 + ci * 9 + kh * 3 + kw]);
}

// ---- main: 512 thr, 8 waves (wc2 x wr2 x wh2), M=128 x N=256 (2 rows), 2 blk/CU -----
// x fp32 read direct; loads for group G+2 issued at END of group G (3-phase latency
// cover); convert+transpose in-register; single barrier per group.
__global__ __launch_bounds__(512, 4)
void conv_min_mfma8(const float* __restrict__ x,
                    const unsigned short* __restrict__ wt3,
                    const float* __restrict__ bias,
                    float* __restrict__ out) {
  __shared__ __align__(16) unsigned short sX[2][2][130][32];   // 33280 B
  __shared__ float sRed[2][256];                               //  2048 B

  const int t   = threadIdx.x;
  const int bid = blockIdx.x;
  const int swz = (bid & 7) * 252 + (bid >> 3);   // 2016 = 8*252, bijective
  const int n   = swz / 63;
  const int oh0 = (swz - n * 63) * 2;             // <=124

  const int lane = t & 63, w = t >> 6;
  const int wc = w & 1;              // co half
  const int wr = (w >> 1) & 1;       // output row within block
  const int wh = w >> 2;             // pixel 64-half
  const int lg = lane >> 4, ln = lane & 15;

  // staging roles: row sr, ci-octet so, column sc (cells c=sc and c=sc+64)
  const int sr = t >> 8;
  const int so = (t >> 6) & 3;
  const int sc = t & 63;

  // B fragment byte-bases into sX (chunk swizzle is ni-invariant)
  const char* Bb[3];
  #pragma unroll
  for (int kw = 0; kw < 3; ++kw) {
    int row = wh * 64 + ln + kw;                  // <=129 (pad rows: finite garbage)
    int ch = lg ^ ((row >> 1) & 3);
    Bb[kw] = (const char*)&sX[0][0][0][0] + wr * 8320 + row * 64 + ch * 16;
  }
  // A fragment lane base (global, L2-resident)
  const unsigned short* wlane = wt3 + wc * 2048 + lane * 8;   // + p*4096 + mi*512

  f32x4 acc[4][4];
  #pragma unroll
  for (int i = 0; i < 4; ++i)
    #pragma unroll
    for (int j = 0; j < 4; ++j)
      acc[i][j] = (f32x4){0.f, 0.f, 0.f, 0.f};

  float svA[8], svB[8];              // ONE group's x data (16 VGPR, ping-pong by WAR)

  auto stage_load = [&](int G) {
    const int h = oh0 + (G >> 1) + sr;            // <=127
    const size_t base = ((size_t)((n * 64 + (G & 1) * 32 + so * 8) * 128 + h)) * 128 + sc;
    #pragma unroll
    for (int j = 0; j < 8; ++j)
      svA[j] = x[base + (size_t)j * 16384];       // 64 lanes x 4B contiguous
    #pragma unroll
    for (int j = 0; j < 8; ++j)
      svB[j] = x[base + 64 + (size_t)j * 16384];
  };
  auto stage_write = [&](int G) {
    const int c0 = sc, c1 = sc + 64;
    const int ch0 = so ^ ((c0 >> 1) & 3);         // baked T2 swizzle (matches reads)
    const int ch1 = so ^ ((c1 >> 1) & 3);
    uint4 vA = make_uint4(packbf2(svA[0], svA[1]), packbf2(svA[2], svA[3]),
                          packbf2(svA[4], svA[5]), packbf2(svA[6], svA[7]));
    uint4 vB = make_uint4(packbf2(svB[0], svB[1]), packbf2(svB[2], svB[3]),
                          packbf2(svB[4], svB[5]), packbf2(svB[6], svB[7]));
    *(uint4*)(&sX[G & 1][sr][c0][ch0 * 8]) = vA;  // conflict-free b128
    *(uint4*)(&sX[G & 1][sr][c1][ch1 * 8]) = vB;
  };

  // prologue: x(0) -> buf0; prefetch x(1) into regs
  stage_load(0);
  stage_write(0);
  stage_load(1);
  asm volatile("s_waitcnt lgkmcnt(0)" ::: "memory");
  __builtin_amdgcn_s_barrier();
  __builtin_amdgcn_sched_barrier(0);

  #pragma unroll
  for (int p = 0; p < 18; ++p) {
    const int G = p / 3, kw = p - G * 3, buf = G & 1;

    bf16x8 af[4], bfr[4];
    #pragma unroll
    for (int mi = 0; mi < 4; ++mi)
      af[mi] = *(const bf16x8*)(wlane + p * 4096 + mi * 512);
    #pragma unroll
    for (int ni = 0; ni < 4; ++ni)
      bfr[ni] = *(const bf16x8*)(Bb[kw] + buf * 16640 + ni * 1024);
    __builtin_amdgcn_s_setprio(1);
    #pragma unroll
    for (int mi = 0; mi < 4; ++mi)
      #pragma unroll
      for (int ni = 0; ni < 4; ++ni)
        acc[mi][ni] = __builtin_amdgcn_mfma_f32_16x16x32_bf16(
            af[mi], bfr[ni], acc[mi][ni], 0, 0, 0);
    __builtin_amdgcn_s_setprio(0);

    if (kw == 2 && G < 5) {
      // write-late: sv holds x(G+1), loaded a full group ago (~3 phases cover)
      stage_write(G + 1);
      // issue-early: reload sv with x(G+2) (WAR reuse of the same registers)
      if (G < 4) stage_load(G + 2);
      __builtin_amdgcn_sched_barrier(0);          // pin loads/writes above the wait
      asm volatile("s_waitcnt lgkmcnt(0)" ::: "memory");
      __builtin_amdgcn_s_barrier();               // next buf staged; cur buf reads done
      __builtin_amdgcn_sched_barrier(0);          // next group's reads stay below
    }
  }

  // epilogue: (acc + bias)*0.5, min over co
  // C/D: col = ln = px within ni-frag, row = lg*4 + r = co within mi-frag
  float bv[4][4];
  #pragma unroll
  for (int mi = 0; mi < 4; ++mi)
    #pragma unroll
    for (int r = 0; r < 4; ++r)
      bv[mi][r] = bias[wc * 64 + mi * 16 + lg * 4 + r];

  #pragma unroll
  for (int ni = 0; ni < 4; ++ni) {
    float m = 3.4e38f;
    #pragma unroll
    for (int mi = 0; mi < 4; ++mi)
      #pragma unroll
      for (int r = 0; r < 4; ++r)
        m = fminf(m, (acc[mi][ni][r] + bv[mi][r]) * 0.5f);
    m = fminf(m, __shfl_xor(m, 16));
    m = fminf(m, __shfl_xor(m, 32));
    if (lg == 0) sRed[wc][wr * 128 + wh * 64 + ni * 16 + ln] = m;
  }
  __syncthreads();
  if (t < 256) {
    int row = t >> 7, c = t & 127;
    if (c < OWw)
      out[((size_t)n * OHh + oh0 + row) * OWw + c] = fminf(sRed[0][t], sRed[1][t]);
  }
}

// ================= fallback (direct-compute path, used only if ws unusable) =========
__global__ __launch_bounds__(256, 2)
void conv_min_fb(const float* __restrict__ x, const float* __restrict__ w,
                 const float* __restrict__ bias, float* __restrict__ out) {
  __shared__ __align__(16) unsigned short sW[128][40];
  __shared__ __align__(16) unsigned short sX[128][40];
  __shared__ float sBias[COUT];
  __shared__ float sRed[2][128];
  const int t = threadIdx.x, bid = blockIdx.x;
  const int n = bid / OHh, oh = bid - n * OHh;
  if (t < COUT) sBias[t] = bias[t];
  const int hq = t & 7, q = t >> 3, c0 = q * 4;
  const int wco = t >> 1, whalf = t & 1;
  const int lane = t & 63, lg = lane >> 4, ln = lane & 15;
  const int wv = t >> 6, wc = wv & 1, wp = wv >> 1;
  f32x4 acc[4][4];
  #pragma unroll
  for (int i = 0; i < 4; ++i)
    #pragma unroll
    for (int j = 0; j < 4; ++j) acc[i][j] = (f32x4){0.f, 0.f, 0.f, 0.f};
  const float* xn = x + (size_t)n * CIN * CH * CW;
  for (int s = 0; s < 18; ++s) {
    const int kw_s = s / 6;
    const int rembase = (s - kw_s * 6) * 32;
    float4 xa[2], xb[2]; int kkp[2];
    #pragma unroll
    for (int pi = 0; pi < 2; ++pi) {
      const int kk = 2 * hq + 16 * pi; kkp[pi] = kk;
      int rem0 = rembase + kk, ci0 = rem0 / 3, kh0 = rem0 - ci0 * 3;
      int rem1 = rem0 + 1, ci1 = rem1 / 3, kh1 = rem1 - ci1 * 3;
      xa[pi] = *(const float4*)(xn + (ci0 * CH + (oh + kh0)) * CW + c0);
      xb[pi] = *(const float4*)(xn + (ci1 * CH + (oh + kh1)) * CW + c0);
    }
    unsigned tmp[8];
    #pragma unroll
    for (int e = 0; e < 8; ++e) {
      int kk = whalf * 16 + 2 * e;
      int rem0 = rembase + kk, ci0 = rem0 / 3, kh0 = rem0 - ci0 * 3;
      int rem1 = rem0 + 1, ci1 = rem1 / 3, kh1 = rem1 - ci1 * 3;
      tmp[e] = (unsigned)f2bf(w[wco * 576 + ci0 * 9 + kh0 * 3 + kw_s]) |
               ((unsigned)f2bf(w[wco * 576 + ci1 * 9 + kh1 * 3 + kw_s]) << 16);
    }
    __syncthreads();
    #pragma unroll
    for (int pi = 0; pi < 2; ++pi)
      #pragma unroll
      for (int j = 0; j < 4; ++j) {
        int p = c0 + j - kw_s;
        unsigned pk = (unsigned)f2bf(((const float*)&xa[pi])[j]) |
                      ((unsigned)f2bf(((const float*)&xb[pi])[j]) << 16);
        if (p >= 0) *(unsigned*)&sX[p][kkp[pi]] = pk;
      }
    *(uint4*)&sW[wco][whalf * 16] = make_uint4(tmp[0], tmp[1], tmp[2], tmp[3]);
    *(uint4*)&sW[wco][whalf * 16 + 8] = make_uint4(tmp[4], tmp[5], tmp[6], tmp[7]);
    __syncthreads();
    bf16x8 af[4], bfr[4];
    #pragma unroll
    for (int mi = 0; mi < 4; ++mi) af[mi] = *(const bf16x8*)&sW[wc * 64 + mi * 16 + ln][lg * 8];
    #pragma unroll
    for (int ni = 0; ni < 4; ++ni) bfr[ni] = *(const bf16x8*)&sX[wp * 64 + ni * 16 + ln][lg * 8];
    #pragma unroll
    for (int mi = 0; mi < 4; ++mi)
      #pragma unroll
      for (int ni = 0; ni < 4; ++ni)
        acc[mi][ni] = __builtin_amdgcn_mfma_f32_16x16x32_bf16(af[mi], bfr[ni], acc[mi][ni], 0, 0, 0);
  }
  #pragma unroll
  for (int ni = 0; ni < 4; ++ni) {
    float m = 3.4e38f;
    #pragma unroll
    for (int mi = 0; mi < 4; ++mi)
      #pragma unroll
      for (int r = 0; r < 4; ++r)
        m = fminf(m, (acc[mi][ni][r] + sBias[wc * 64 + mi * 16 + lg * 4 + r]) * 0.5f);
    m = fminf(m, __shfl_xor(m, 16));
    m = fminf(m, __shfl_xor(m, 32));
    if (lg == 0) sRed[wc][wp * 64 + ni * 16 + ln] = m;
  }
  __syncthreads();
  if (t < OWw) out[(size_t)(n * OHh + oh) * OWw + t] = fminf(sRed[0][t], sRed[1][t]);
}

extern "C" void kernel_launch(void* const* d_in, const int* in_sizes, int n_in,
                              void* d_out, int out_size, void* d_ws, size_t ws_size,
                              hipStream_t stream) {
  const float* x    = (const float*)d_in[0];
  const float* w    = (const float*)d_in[1];
  const float* bias = (const float*)d_in[2];
  float* out = (float*)d_out;

  const size_t WT_BYTES = (size_t)COUT * KTOT * 2;   // 147,456

  if (d_ws && ws_size >= WT_BYTES) {
    unsigned short* wt3 = (unsigned short*)d_ws;
    prep_wt3_kernel<<<(COUT * KTOT + 255) / 256, 256, 0, stream>>>(w, wt3);
    conv_min_mfma8<<<2016, 512, 0, stream>>>(x, wt3, bias, out);
  } else {
    conv_min_fb<<<CN * OHh, 256, 0, stream>>>(x, w, bias, out);
  }
}

// Round 8
// 92.858 us; speedup vs baseline: 1.7494x; 1.7494x over previous
//
#include <hip/hip_runtime.h>
#include <hip/hip_bf16.h>

constexpr int CN   = 32;
constexpr int CIN  = 64;
constexpr int CH   = 128;
constexpr int CW   = 128;
constexpr int COUT = 128;
constexpr int OHh  = 126;
constexpr int OWw  = 126;
constexpr int KTOT = 576;

typedef __attribute__((ext_vector_type(8))) short bf16x8;
typedef __attribute__((ext_vector_type(4))) float f32x4;

__device__ __forceinline__ unsigned short f2bf(float f) {
  union { float f; unsigned u; } v; v.f = f;
  unsigned u = v.u;
  u += 0x7FFFu + ((u >> 16) & 1u);   // RNE
  return (unsigned short)(u >> 16);
}

__device__ __forceinline__ unsigned packbf2(float a, float b) {
  union { __hip_bfloat162 h; unsigned u; } v;
  v.h = __float22bfloat162_rn(make_float2(a, b));   // v_cvt_pk_bf16_f32
  return v.u;
}

// ---- prep: W -> wt3, A-fragment-ordered: [p:18][wc:2][mi:4][lane:64][j:8] -----------
// p = G*3+kw, G = kh*2+half; co = wc*64+mi*16+(lane&15); ci = half*32+(lane>>4)*8+j.
__global__ void prep_wt3_kernel(const float* __restrict__ w,
                                unsigned short* __restrict__ wt3) {
  int e = blockIdx.x * 256 + threadIdx.x;
  if (e >= COUT * KTOT) return;
  int j = e & 7, lane = (e >> 3) & 63, mi = (e >> 9) & 3, wc = (e >> 11) & 1;
  int p = e >> 12;                 // 0..17
  int G = p / 3, kw = p - G * 3;
  int kh = G >> 1, half = G & 1;
  int co = wc * 64 + mi * 16 + (lane & 15);
  int ci = half * 32 + (lane >> 4) * 8 + j;
  wt3[e] = f2bf(w[co * 576 + ci * 9 + kh * 3 + kw]);
}

// ---- main: 256 thr, 4 waves (2wc x 2wp), tile 128co x 128px (1 row), 4 blk/CU -------
// x fp32 read direct at kw=0, converted+transposed in-register, written kw=2;
// af streamed from global wt3 (L1/L2); one barrier per group; TLP from 4 blocks.
__global__ __launch_bounds__(256, 4)
void conv_min_mfma9(const float* __restrict__ x,
                    const unsigned short* __restrict__ wt3,
                    const float* __restrict__ bias,
                    float* __restrict__ out) {
  __shared__ __align__(16) unsigned short sX[2][130][32];   // 16640 B
  __shared__ float sRed[2][128];                            //  1024 B

  const int t   = threadIdx.x;
  const int bid = blockIdx.x;
  const int swz = (bid & 7) * 504 + (bid >> 3);   // 4032 = 8*504, bijective
  const int n   = swz / OHh;
  const int oh  = swz - n * OHh;                  // 0..125

  const int lane = t & 63, w = t >> 6;
  const int wc = w & 1;              // co half
  const int wp = w >> 1;             // px half
  const int lg = lane >> 4, ln = lane & 15;

  // staging roles: c = t&127, octet base o0 = (t>>7)*2 (handles octets o0, o0+1)
  const int sc = t & 127;
  const int o0 = (t >> 7) * 2;

  // B fragment byte-offsets into sX (chunk swizzle is ni-invariant: +16 rows keeps XOR)
  int Bb[3];
  #pragma unroll
  for (int kw = 0; kw < 3; ++kw) {
    int row = wp * 64 + ln + kw;                  // <=129 (pad rows: finite garbage)
    int ch = lg ^ ((row >> 1) & 3);
    Bb[kw] = row * 64 + ch * 16;                  // + dbuf*8320 + ni*1024
  }
  // A fragment lane base (global, L2-resident)
  const unsigned short* wlane = wt3 + wc * 2048 + lane * 8;   // + p*4096 + mi*512

  f32x4 acc[4][4];
  #pragma unroll
  for (int i = 0; i < 4; ++i)
    #pragma unroll
    for (int j = 0; j < 4; ++j)
      acc[i][j] = (f32x4){0.f, 0.f, 0.f, 0.f};

  float sv[2][8];                    // one group's x slice per thread (16 VGPR)

  auto loadX = [&](int G) {          // 16 coalesced fp32 loads (issued, not waited)
    const int h = oh + (G >> 1);                  // <=127
    #pragma unroll
    for (int r = 0; r < 2; ++r) {
      const size_t base =
          ((size_t)((n * 64 + (G & 1) * 32 + (o0 + r) * 8) * 128 + h)) * 128 + sc;
      #pragma unroll
      for (int j = 0; j < 8; ++j)
        sv[r][j] = x[base + (size_t)j * 16384];
    }
  };
  auto writeX = [&](int dbuf) {      // 2 conflict-free ds_write_b128
    #pragma unroll
    for (int r = 0; r < 2; ++r) {
      const int ch = (o0 + r) ^ ((sc >> 1) & 3);  // baked T2 swizzle (matches reads)
      uint4 v = make_uint4(packbf2(sv[r][0], sv[r][1]), packbf2(sv[r][2], sv[r][3]),
                           packbf2(sv[r][4], sv[r][5]), packbf2(sv[r][6], sv[r][7]));
      *(uint4*)(&sX[dbuf][sc][ch * 8]) = v;
    }
  };

  // prologue: stage group 0 into buf 0 (one-time stall, covered by other blocks)
  loadX(0);
  writeX(0);
  asm volatile("s_waitcnt lgkmcnt(0)" ::: "memory");
  __builtin_amdgcn_s_barrier();
  __builtin_amdgcn_sched_barrier(0);

  #pragma unroll
  for (int p = 0; p < 18; ++p) {
    const int G = p / 3, kw = p - G * 3, dbuf = G & 1;

    if (kw == 0 && G < 5)
      loadX(G + 1);                  // issue-early; consumed at kw=2 (~3 phases cover)

    bf16x8 bfr[4];
    #pragma unroll
    for (int ni = 0; ni < 4; ++ni)
      bfr[ni] = *(const bf16x8*)((const char*)&sX[0][0][0] +
                                 dbuf * 8320 + Bb[kw] + ni * 1024);
    __builtin_amdgcn_s_setprio(1);
    #pragma unroll
    for (int mi = 0; mi < 4; ++mi) {   // af streamed: 1 live fragment (4 VGPR)
      bf16x8 af = *(const bf16x8*)(wlane + p * 4096 + mi * 512);
      #pragma unroll
      for (int ni = 0; ni < 4; ++ni)
        acc[mi][ni] = __builtin_amdgcn_mfma_f32_16x16x32_bf16(
            af, bfr[ni], acc[mi][ni], 0, 0, 0);
    }
    __builtin_amdgcn_s_setprio(0);

    if (kw == 2 && G < 5) {
      writeX(dbuf ^ 1);              // write-late into next buffer
      asm volatile("s_waitcnt lgkmcnt(0)" ::: "memory");
      __builtin_amdgcn_s_barrier();  // next buf staged; cur buf reads done
      __builtin_amdgcn_sched_barrier(0);
    }
  }

  // epilogue: (acc + bias)*0.5, min over co
  // C/D: col = ln = px within ni-frag, row = lg*4 + r = co within mi-frag
  float bv[4][4];
  #pragma unroll
  for (int mi = 0; mi < 4; ++mi)
    #pragma unroll
    for (int r = 0; r < 4; ++r)
      bv[mi][r] = bias[wc * 64 + mi * 16 + lg * 4 + r];

  #pragma unroll
  for (int ni = 0; ni < 4; ++ni) {
    float m = 3.4e38f;
    #pragma unroll
    for (int mi = 0; mi < 4; ++mi)
      #pragma unroll
      for (int r = 0; r < 4; ++r)
        m = fminf(m, (acc[mi][ni][r] + bv[mi][r]) * 0.5f);
    m = fminf(m, __shfl_xor(m, 16));
    m = fminf(m, __shfl_xor(m, 32));
    if (lg == 0) sRed[wc][wp * 64 + ni * 16 + ln] = m;
  }
  __syncthreads();
  if (t < OWw)
    out[((size_t)n * OHh + oh) * OWw + t] = fminf(sRed[0][t], sRed[1][t]);
}

// ================= fallback (direct-compute path, used only if ws unusable) =========
__global__ __launch_bounds__(256, 2)
void conv_min_fb(const float* __restrict__ x, const float* __restrict__ w,
                 const float* __restrict__ bias, float* __restrict__ out) {
  __shared__ __align__(16) unsigned short sW[128][40];
  __shared__ __align__(16) unsigned short sX[128][40];
  __shared__ float sBias[COUT];
  __shared__ float sRed[2][128];
  const int t = threadIdx.x, bid = blockIdx.x;
  const int n = bid / OHh, oh = bid - n * OHh;
  if (t < COUT) sBias[t] = bias[t];
  const int hq = t & 7, q = t >> 3, c0 = q * 4;
  const int wco = t >> 1, whalf = t & 1;
  const int lane = t & 63, lg = lane >> 4, ln = lane & 15;
  const int wv = t >> 6, wc = wv & 1, wp = wv >> 1;
  f32x4 acc[4][4];
  #pragma unroll
  for (int i = 0; i < 4; ++i)
    #pragma unroll
    for (int j = 0; j < 4; ++j) acc[i][j] = (f32x4){0.f, 0.f, 0.f, 0.f};
  const float* xn = x + (size_t)n * CIN * CH * CW;
  for (int s = 0; s < 18; ++s) {
    const int kw_s = s / 6;
    const int rembase = (s - kw_s * 6) * 32;
    float4 xa[2], xb[2]; int kkp[2];
    #pragma unroll
    for (int pi = 0; pi < 2; ++pi) {
      const int kk = 2 * hq + 16 * pi; kkp[pi] = kk;
      int rem0 = rembase + kk, ci0 = rem0 / 3, kh0 = rem0 - ci0 * 3;
      int rem1 = rem0 + 1, ci1 = rem1 / 3, kh1 = rem1 - ci1 * 3;
      xa[pi] = *(const float4*)(xn + (ci0 * CH + (oh + kh0)) * CW + c0);
      xb[pi] = *(const float4*)(xn + (ci1 * CH + (oh + kh1)) * CW + c0);
    }
    unsigned tmp[8];
    #pragma unroll
    for (int e = 0; e < 8; ++e) {
      int kk = whalf * 16 + 2 * e;
      int rem0 = rembase + kk, ci0 = rem0 / 3, kh0 = rem0 - ci0 * 3;
      int rem1 = rem0 + 1, ci1 = rem1 / 3, kh1 = rem1 - ci1 * 3;
      tmp[e] = (unsigned)f2bf(w[wco * 576 + ci0 * 9 + kh0 * 3 + kw_s]) |
               ((unsigned)f2bf(w[wco * 576 + ci1 * 9 + kh1 * 3 + kw_s]) << 16);
    }
    __syncthreads();
    #pragma unroll
    for (int pi = 0; pi < 2; ++pi)
      #pragma unroll
      for (int j = 0; j < 4; ++j) {
        int p = c0 + j - kw_s;
        unsigned pk = (unsigned)f2bf(((const float*)&xa[pi])[j]) |
                      ((unsigned)f2bf(((const float*)&xb[pi])[j]) << 16);
        if (p >= 0) *(unsigned*)&sX[p][kkp[pi]] = pk;
      }
    *(uint4*)&sW[wco][whalf * 16] = make_uint4(tmp[0], tmp[1], tmp[2], tmp[3]);
    *(uint4*)&sW[wco][whalf * 16 + 8] = make_uint4(tmp[4], tmp[5], tmp[6], tmp[7]);
    __syncthreads();
    bf16x8 af[4], bfr[4];
    #pragma unroll
    for (int mi = 0; mi < 4; ++mi) af[mi] = *(const bf16x8*)&sW[wc * 64 + mi * 16 + ln][lg * 8];
    #pragma unroll
    for (int ni = 0; ni < 4; ++ni) bfr[ni] = *(const bf16x8*)&sX[wp * 64 + ni * 16 + ln][lg * 8];
    #pragma unroll
    for (int mi = 0; mi < 4; ++mi)
      #pragma unroll
      for (int ni = 0; ni < 4; ++ni)
        acc[mi][ni] = __builtin_amdgcn_mfma_f32_16x16x32_bf16(af[mi], bfr[ni], acc[mi][ni], 0, 0, 0);
  }
  #pragma unroll
  for (int ni = 0; ni < 4; ++ni) {
    float m = 3.4e38f;
    #pragma unroll
    for (int mi = 0; mi < 4; ++mi)
      #pragma unroll
      for (int r = 0; r < 4; ++r)
        m = fminf(m, (acc[mi][ni][r] + sBias[wc * 64 + mi * 16 + lg * 4 + r]) * 0.5f);
    m = fminf(m, __shfl_xor(m, 16));
    m = fminf(m, __shfl_xor(m, 32));
    if (lg == 0) sRed[wc][wp * 64 + ni * 16 + ln] = m;
  }
  __syncthreads();
  if (t < OWw) out[(size_t)(n * OHh + oh) * OWw + t] = fminf(sRed[0][t], sRed[1][t]);
}

extern "C" void kernel_launch(void* const* d_in, const int* in_sizes, int n_in,
                              void* d_out, int out_size, void* d_ws, size_t ws_size,
                              hipStream_t stream) {
  const float* x    = (const float*)d_in[0];
  const float* w    = (const float*)d_in[1];
  const float* bias = (const float*)d_in[2];
  float* out = (float*)d_out;

  const size_t WT_BYTES = (size_t)COUT * KTOT * 2;   // 147,456

  if (d_ws && ws_size >= WT_BYTES) {
    unsigned short* wt3 = (unsigned short*)d_ws;
    prep_wt3_kernel<<<(COUT * KTOT + 255) / 256, 256, 0, stream>>>(w, wt3);
    conv_min_mfma9<<<CN * OHh, 256, 0, stream>>>(x, wt3, bias, out);
  } else {
    conv_min_fb<<<CN * OHh, 256, 0, stream>>>(x, w, bias, out);
  }
}